// Round 11
// baseline (305.765 us; speedup 1.0000x reference)
//
#include <hip/hip_runtime.h>
#include <stdint.h>

// AttentionBlock: GN -> QKV -> softmax(QK^T/sqrt(C)) V -> proj + residual
// B=4, C=256, H=W=64, N=4096, groups=8 (32 ch/group)
// All matmuls bf16 MFMA (fp32 accumulate). fp32 threshold 0.1 absmax.
//
// Round 11: attn on mfma_f32_32x32x16 (32 q-rows/wave -> 2x FLOP per LDS
// byte, the round-10 binding resource) + chunk-major K/V LDS tiles
// ([chunk16B][row]) so every B-fragment read is a contiguous 512B block per
// 32-lane group: conflict-free, no swizzle, linear global_load_lds staging.
// 4 waves = 2 rowgroups x 2 key-halves; static-max softmax; O/l merged in
// epilogue via LDS reuse.

#define B_ 4
#define C_ 256
#define N_ 4096
#define KVB 32

using bf16x8 = __attribute__((ext_vector_type(8))) __bf16;
using f32x4  = __attribute__((ext_vector_type(4))) float;
using f32x16 = __attribute__((ext_vector_type(16))) float;

__device__ __forceinline__ uint16_t f2bf(float f) {
    uint32_t u = __float_as_uint(f);
    u = (u + 0x7fffu + ((u >> 16) & 1u)) >> 16;   // RNE
    return (uint16_t)u;
}

__device__ __forceinline__ f32x4 mfma16(bf16x8 a, bf16x8 b, f32x4 c) {
    return __builtin_amdgcn_mfma_f32_16x16x32_bf16(a, b, c, 0, 0, 0);
}

__device__ __forceinline__ f32x16 mfma32(bf16x8 a, bf16x8 b, f32x16 c) {
    return __builtin_amdgcn_mfma_f32_32x32x16_bf16(a, b, c, 0, 0, 0);
}

__device__ __forceinline__ void gload16(const void* g, void* l) {
    __builtin_amdgcn_global_load_lds(
        (const __attribute__((address_space(1))) uint32_t*)g,
        (__attribute__((address_space(3))) uint32_t*)l, 16, 0, 0);
}

// ---------------- cast weights to bf16 ----------------
__global__ __launch_bounds__(256) void cast_weights(
        const float* __restrict__ qkvw, const float* __restrict__ projw,
        uint16_t* __restrict__ qkvwb, uint16_t* __restrict__ projwb) {
    int i = blockIdx.x * 256 + threadIdx.x;
    if (i < 768 * 256) qkvwb[i] = f2bf(qkvw[i]);
    int j = i - 768 * 256;
    if (j >= 0 && j < 256 * 256) projwb[j] = f2bf(projw[j]);
}

// ---------------- GroupNorm stats, two-stage ----------------
__global__ __launch_bounds__(256) void gn_stats1(const float* __restrict__ x,
                                                 float2* __restrict__ part) {
    int i = blockIdx.x;
    const float4* p = reinterpret_cast<const float4*>(x + (size_t)i * 4096);
    float s = 0.f, ss = 0.f;
    #pragma unroll
    for (int j = 0; j < 4; j++) {
        float4 v = p[threadIdx.x + j * 256];
        s  += v.x + v.y + v.z + v.w;
        ss += v.x*v.x + v.y*v.y + v.z*v.z + v.w*v.w;
    }
    #pragma unroll
    for (int d = 32; d > 0; d >>= 1) { s += __shfl_down(s, d); ss += __shfl_down(ss, d); }
    __shared__ float rs[4], rss[4];
    int wid = threadIdx.x >> 6;
    if ((threadIdx.x & 63) == 0) { rs[wid] = s; rss[wid] = ss; }
    __syncthreads();
    if (threadIdx.x == 0) {
        float2 o;
        o.x = rs[0] + rs[1] + rs[2] + rs[3];
        o.y = rss[0] + rss[1] + rss[2] + rss[3];
        part[i] = o;
    }
}
__global__ __launch_bounds__(1024) void gn_stats2(const float2* __restrict__ part,
                                                  float* __restrict__ stats) {
    int t = threadIdx.x;
    int g = t >> 5, j = t & 31;
    float2 v = part[g * 32 + j];
    float s = v.x, ss = v.y;
    #pragma unroll
    for (int d = 16; d > 0; d >>= 1) { s += __shfl_xor(s, d); ss += __shfl_xor(ss, d); }
    if (j == 0) {
        float mean = s / 131072.f;
        float var  = ss / 131072.f - mean * mean;
        stats[g * 2]     = mean;
        stats[g * 2 + 1] = rsqrtf(var + 1e-5f);
    }
}

// ---------------- GN apply + transpose: hT[b][n][c] bf16 ----------------
__global__ __launch_bounds__(256) void gn_apply(
        const float* __restrict__ x, const float* __restrict__ gnw,
        const float* __restrict__ gnb, const float* __restrict__ stats,
        uint16_t* __restrict__ hT) {
    int nb = blockIdx.x * 64, cb = blockIdx.y * 64, b = blockIdx.z;
    __shared__ uint16_t lds[64][64];          // [n][c]
    int t = threadIdx.x;
    int c_l = t >> 4;
    int n4  = (t & 15) * 4;
    #pragma unroll
    for (int i = 0; i < 4; i++) {
        int c = cb + c_l + 16 * i;
        int sg = b * 8 + (c >> 5);
        float mean = stats[sg * 2], rstd = stats[sg * 2 + 1];
        float sc = gnw[c] * rstd;
        float sh = gnb[c] - mean * sc;
        float4 v = *reinterpret_cast<const float4*>(x + ((size_t)b * C_ + c) * N_ + nb + n4);
        lds[n4 + 0][c_l + 16 * i] = f2bf(fmaf(v.x, sc, sh));
        lds[n4 + 1][c_l + 16 * i] = f2bf(fmaf(v.y, sc, sh));
        lds[n4 + 2][c_l + 16 * i] = f2bf(fmaf(v.z, sc, sh));
        lds[n4 + 3][c_l + 16 * i] = f2bf(fmaf(v.w, sc, sh));
    }
    __syncthreads();
    int n_l = t >> 2, c16 = (t & 3) * 16;
    uint4* dst = reinterpret_cast<uint4*>(hT + ((size_t)b * N_ + nb + n_l) * C_ + cb + c16);
    const uint4* sp = reinterpret_cast<const uint4*>(&lds[n_l][c16]);
    dst[0] = sp[0]; dst[1] = sp[1];
}

// ---------------- QKV GEMM ----------------
// q,k transposed [n][o]; q pre-scaled by 1/16 (softmax scale). v kept [o'][n].
__global__ __launch_bounds__(256) void qkv_gemm(
        const uint16_t* __restrict__ Wb, const float* __restrict__ qkvb,
        const uint16_t* __restrict__ hT, uint16_t* __restrict__ qT,
        uint16_t* __restrict__ kT, uint16_t* __restrict__ vO) {
    int nt = blockIdx.x, ot = blockIdx.y, b = blockIdx.z;
    int lane = threadIdx.x & 63, w = threadIdx.x >> 6;
    int l15 = lane & 15, g = lane >> 4;
    const uint16_t* hTb = hT + (size_t)b * N_ * C_;
    f32x4 z = {0.f, 0.f, 0.f, 0.f};
    f32x4 acc[4] = {z, z, z, z};

    if (ot < 8) {   // q,k : D[row=n][col=o]
        int nrow = nt * 64 + w * 16 + l15;
        const bf16x8* Arow = reinterpret_cast<const bf16x8*>(hTb + (size_t)nrow * C_);
        #pragma unroll
        for (int kk = 0; kk < 8; kk++) {
            bf16x8 a = Arow[kk * 4 + g];
            #pragma unroll
            for (int j = 0; j < 4; j++) {
                int orow = ot * 64 + j * 16 + l15;
                bf16x8 bfr = reinterpret_cast<const bf16x8*>(Wb + (size_t)orow * C_)[kk * 4 + g];
                acc[j] = mfma16(a, bfr, acc[j]);
            }
        }
        #pragma unroll
        for (int j = 0; j < 4; j++) {
            int o = ot * 64 + j * 16 + l15;
            float bias = qkvb[o];
            bool isq = (o < 256);
            float scl = isq ? 0.0625f : 1.0f;
            uint16_t* dst = isq ? (qT + (size_t)b * N_ * C_ + o)
                                : (kT + (size_t)b * N_ * C_ + (o - 256));
            #pragma unroll
            for (int r = 0; r < 4; r++) {
                int n = nt * 64 + w * 16 + g * 4 + r;
                dst[(size_t)n * C_] = f2bf((acc[j][r] + bias) * scl);
            }
        }
    } else {        // v : D[row=o'][col=n]
        int orow = ot * 64 + w * 16 + l15;   // 512..767
        const bf16x8* Arow = reinterpret_cast<const bf16x8*>(Wb + (size_t)orow * C_);
        #pragma unroll
        for (int kk = 0; kk < 8; kk++) {
            bf16x8 a = Arow[kk * 4 + g];
            #pragma unroll
            for (int j = 0; j < 4; j++) {
                int nrow = nt * 64 + j * 16 + l15;
                bf16x8 bfr = reinterpret_cast<const bf16x8*>(hTb + (size_t)nrow * C_)[kk * 4 + g];
                acc[j] = mfma16(a, bfr, acc[j]);
            }
        }
        #pragma unroll
        for (int j = 0; j < 4; j++) {
            #pragma unroll
            for (int r = 0; r < 4; r++) {
                int o = ot * 64 + w * 16 + g * 4 + r;
                int n = nt * 64 + j * 16 + l15;
                vO[(size_t)b * C_ * N_ + (size_t)(o - 512) * N_ + n] = f2bf(acc[j][r] + qkvb[o]);
            }
        }
    }
}

// ---------------- Flash attention: 32x32 MFMA, chunk-major LDS ----------------
// Block 256 thr = 4 waves: rowgroup rg = w&1 (32 q-rows), key half h = w>>1
// (64 of 128 key tiles). Per (buf,half):
//   Kt: [32 chunk16B][32 key][8 ch]  (chunk-major: B-frag reads contiguous)
//   Vt: [4 chunk16B][256 ch][8 key]  (chunk-major: A-frag reads contiguous)
// QK^T: D[row=qrow][col=key], A=Q (regs, 64 VGPR), B=K from Kt. 16 MFMAs.
// softmax: static max m=0 (q pre-scaled), p=exp, per-lane lsum[16] partials.
// PV: D[row=ch][col=qrow], A=V from Vt, B=P^T from plds (pitch 40 u16:
// writes 2-way, reads minimum-phase). 16 MFMAs. acc = 8 x f32x16.
// Epilogue: xor-reduce lsum, row sums via lbuf LDS; h=1 writes O to Olds
// (f32, pitch 260, aliases dead Kt/Vt), h=0 merges + stores h2T.
__global__ __launch_bounds__(256, 1) void attn_kernel(
        const uint16_t* __restrict__ qT, const uint16_t* __restrict__ kT,
        const uint16_t* __restrict__ vO, uint16_t* __restrict__ h2T) {
    int blk = blockIdx.x;
    int xx = blk & 7;
    int b  = xx >> 1;
    int qt = (blk >> 3) * 2 + (xx & 1);       // 0..63
    int lane = threadIdx.x & 63, w = threadIdx.x >> 6;   // w in 0..3
    int rg = w & 1, h = w >> 1;
    int l31 = lane & 31, g5 = lane >> 5;
    const uint16_t* qTb = qT + (size_t)b * N_ * C_;
    const uint16_t* kTb = kT + (size_t)b * N_ * C_;
    const uint16_t* vb  = vO + (size_t)b * C_ * N_;
    int nb = qt * 64 + rg * 32;

    __shared__ __align__(16) char smem[141312];
    uint16_t* KtB = reinterpret_cast<uint16_t*>(smem);            // [2buf][2h][8192]
    uint16_t* VtB = reinterpret_cast<uint16_t*>(smem + 65536);    // [2buf][2h][8192]
    uint16_t* plw = reinterpret_cast<uint16_t*>(smem + 131072) + w * 1280;  // [32][40]

    // Q fragments: A[row=l31][k=s*16 + g5*8 + j]
    bf16x8 afr[16];
    {
        const uint16_t* qrow = qTb + (size_t)(nb + l31) * C_;
        #pragma unroll
        for (int s = 0; s < 16; s++)
            afr[s] = *reinterpret_cast<const bf16x8*>(qrow + s * 16 + g5 * 8);
    }

    f32x16 acc[8];
    #pragma unroll
    for (int i = 0; i < 8; i++) acc[i] = (f32x16){};
    float lsum[16];
    #pragma unroll
    for (int i = 0; i < 16; i++) lsum[i] = 0.f;

    // wave (rg,h) stages half h's next tile (linear dests, chunk-major)
    auto stage = [&](int bufh, int mb) {
        uint16_t* Ktp = KtB + bufh * 8192;
        uint16_t* Vtp = VtB + bufh * 8192;
        #pragma unroll
        for (int i = 0; i < 8; i++) {         // K: 2 chunk-cols x 32 keys / instr
            int c2 = rg * 16 + i * 2;
            gload16(kTb + (size_t)(mb + l31) * C_ + (c2 + g5) * 8, Ktp + c2 * 256);
        }
        #pragma unroll
        for (int i = 0; i < 8; i++) {         // V: 1 chunk x 64 ch / instr
            int c   = i >> 1;
            int cb3 = rg * 128 + (i & 1) * 64;
            gload16(vb + (size_t)(cb3 + lane) * N_ + mb + c * 8, Vtp + c * 2048 + cb3 * 8);
        }
    };

    stage(h, h * 64 * KVB);
    __syncthreads();

    for (int mt = 0; mt < 64; mt++) {
        int buf = mt & 1;
        if (mt + 1 < 64) stage((buf ^ 1) * 2 + h, (h * 64 + mt + 1) * KVB);
        const uint16_t* Ktp = KtB + (buf * 2 + h) * 8192;
        const uint16_t* Vtp = VtB + (buf * 2 + h) * 8192;

        // ---- QK^T: 16 ch-steps, B-frag = contiguous 512B/group ----
        f32x16 sc = (f32x16){};
        #pragma unroll
        for (int s = 0; s < 16; s++) {
            bf16x8 kfr = *reinterpret_cast<const bf16x8*>(Ktp + (s * 2 + g5) * 256 + l31 * 8);
            sc = mfma32(afr[s], kfr, sc);
        }

        // ---- static-max softmax: p=exp(score), lane-local l partials ----
        #pragma unroll
        for (int reg = 0; reg < 16; reg++) {
            float p = __expf(sc[reg]);
            lsum[reg] += p;
            int row = (reg & 3) + 8 * (reg >> 2) + 4 * g5;
            plw[row * 40 + l31] = f2bf(p);
        }

        bf16x8 pf0 = *reinterpret_cast<const bf16x8*>(plw + l31 * 40 + g5 * 8);
        bf16x8 pf1 = *reinterpret_cast<const bf16x8*>(plw + l31 * 40 + 16 + g5 * 8);

        // ---- PV: A=V chunk-major (contiguous), B=P^T ----
        #pragma unroll
        for (int ct = 0; ct < 8; ct++) {
            int ch8 = (ct * 32 + l31) * 8;
            bf16x8 v0 = *reinterpret_cast<const bf16x8*>(Vtp + g5 * 2048 + ch8);
            bf16x8 v1 = *reinterpret_cast<const bf16x8*>(Vtp + (2 + g5) * 2048 + ch8);
            acc[ct] = mfma32(v0, pf0, acc[ct]);
            acc[ct] = mfma32(v1, pf1, acc[ct]);
        }

        __syncthreads();   // drains vmcnt (stage done); both halves advance
    }

    // ---- epilogue ----
    #pragma unroll
    for (int d = 1; d < 32; d <<= 1) {
        #pragma unroll
        for (int reg = 0; reg < 16; reg++) lsum[reg] += __shfl_xor(lsum[reg], d);
    }
    float* Olds = reinterpret_cast<float*>(smem);            // [2rg][32 qrow][260]
    float* lbuf = reinterpret_cast<float*>(smem + 66560);    // [2h][2rg][32]
    if ((lane & 31) == 0) {
        #pragma unroll
        for (int reg = 0; reg < 16; reg++) {
            int row = (reg & 3) + 8 * (reg >> 2) + 4 * g5;
            lbuf[(h * 2 + rg) * 32 + row] = lsum[reg];
        }
    }
    if (h == 1) {
        #pragma unroll
        for (int ct = 0; ct < 8; ct++) {
            #pragma unroll
            for (int qd = 0; qd < 4; qd++) {
                f32x4 v = {acc[ct][qd * 4 + 0], acc[ct][qd * 4 + 1],
                           acc[ct][qd * 4 + 2], acc[ct][qd * 4 + 3]};
                *reinterpret_cast<f32x4*>(
                    &Olds[(size_t)(rg * 32 + l31) * 260 + ct * 32 + qd * 8 + 4 * g5]) = v;
            }
        }
    }
    __syncthreads();
    if (h == 0) {
        float inv = 1.0f / (lbuf[rg * 32 + l31] + lbuf[(2 + rg) * 32 + l31]);
        uint16_t* rowp = h2T + ((size_t)b * N_ + nb + l31) * C_;
        #pragma unroll
        for (int ct = 0; ct < 8; ct++) {
            #pragma unroll
            for (int qd = 0; qd < 4; qd++) {
                f32x4 o = *reinterpret_cast<const f32x4*>(
                    &Olds[(size_t)(rg * 32 + l31) * 260 + ct * 32 + qd * 8 + 4 * g5]);
                uint32_t lo = f2bf((acc[ct][qd * 4 + 0] + o[0]) * inv) |
                              ((uint32_t)f2bf((acc[ct][qd * 4 + 1] + o[1]) * inv) << 16);
                uint32_t hi = f2bf((acc[ct][qd * 4 + 2] + o[2]) * inv) |
                              ((uint32_t)f2bf((acc[ct][qd * 4 + 3] + o[3]) * inv) << 16);
                uint2 val = {lo, hi};
                *reinterpret_cast<uint2*>(rowp + ct * 32 + qd * 8 + 4 * g5) = val;
            }
        }
    }
}

// ---------------- proj GEMM + bias + residual ----------------
__global__ __launch_bounds__(256) void proj_gemm(
        const uint16_t* __restrict__ Pwb, const float* __restrict__ pb,
        const uint16_t* __restrict__ h2T, const float* __restrict__ x,
        float* __restrict__ out) {
    int nt = blockIdx.x, ct = blockIdx.y, b = blockIdx.z;
    int lane = threadIdx.x & 63, w = threadIdx.x >> 6;
    int l15 = lane & 15, g = lane >> 4;
    const uint16_t* h2Tb = h2T + (size_t)b * N_ * C_;
    f32x4 z = {0.f, 0.f, 0.f, 0.f};
    f32x4 acc[4] = {z, z, z, z};
    int crow = ct * 64 + w * 16 + l15;
    const bf16x8* Arow = reinterpret_cast<const bf16x8*>(Pwb + (size_t)crow * C_);
    #pragma unroll
    for (int kk = 0; kk < 8; kk++) {
        bf16x8 a = Arow[kk * 4 + g];
        #pragma unroll
        for (int j = 0; j < 4; j++) {
            bf16x8 bfr = reinterpret_cast<const bf16x8*>(
                h2Tb + (size_t)(nt * 64 + j * 16 + l15) * C_)[kk * 4 + g];
            acc[j] = mfma16(a, bfr, acc[j]);
        }
    }
    #pragma unroll
    for (int j = 0; j < 4; j++) {
        #pragma unroll
        for (int r = 0; r < 4; r++) {
            int c = ct * 64 + w * 16 + g * 4 + r;
            int n = nt * 64 + j * 16 + l15;
            size_t idx = ((size_t)b * C_ + c) * N_ + n;
            out[idx] = x[idx] + acc[j][r] + pb[c];
        }
    }
}

extern "C" void kernel_launch(void* const* d_in, const int* in_sizes, int n_in,
                              void* d_out, int out_size, void* d_ws, size_t ws_size,
                              hipStream_t stream) {
    const float* x      = (const float*)d_in[0];
    const float* gn_w   = (const float*)d_in[1];
    const float* gn_b   = (const float*)d_in[2];
    const float* qkv_w  = (const float*)d_in[3];
    const float* qkv_b  = (const float*)d_in[4];
    const float* proj_w = (const float*)d_in[5];
    const float* proj_b = (const float*)d_in[6];
    float* out = (float*)d_out;

    char* ws = (char*)d_ws;
    float*    stats  = (float*)(ws);                          // 256 B
    float2*   part   = (float2*)(ws + 8192);                  // 8 KB
    uint16_t* qkvwb  = (uint16_t*)(ws + 65536);               // 384 KB
    uint16_t* projwb = (uint16_t*)(ws + 65536 + 768 * 256 * 2);
    uint16_t* hT     = (uint16_t*)(ws + (size_t)(1)  * (1 << 20));  // 8 MB [B][N][C]
    uint16_t* qT     = (uint16_t*)(ws + (size_t)(9)  * (1 << 20));  // 8 MB [B][N][C]
    uint16_t* kT     = (uint16_t*)(ws + (size_t)(17) * (1 << 20));  // 8 MB [B][N][C]
    uint16_t* vO     = (uint16_t*)(ws + (size_t)(25) * (1 << 20));  // 8 MB [B][C][N]
    uint16_t* h2T    = (uint16_t*)(ws + (size_t)(33) * (1 << 20));  // 8 MB [B][N][C]

    cast_weights<<<dim3(1024), dim3(256), 0, stream>>>(qkv_w, proj_w, qkvwb, projwb);
    gn_stats1<<<dim3(1024), dim3(256), 0, stream>>>(x, part);
    gn_stats2<<<dim3(1), dim3(1024), 0, stream>>>(part, stats);
    gn_apply<<<dim3(64, 4, 4), dim3(256), 0, stream>>>(x, gn_w, gn_b, stats, hT);
    qkv_gemm<<<dim3(64, 12, 4), dim3(256), 0, stream>>>(qkvwb, qkv_b, hT, qT, kT, vO);
    attn_kernel<<<dim3(256), dim3(256), 0, stream>>>(qT, kT, vO, h2T);
    proj_gemm<<<dim3(64, 4, 4), dim3(256), 0, stream>>>(projwb, proj_b, h2T, x, out);
}

// Round 12
// 304.156 us; speedup vs baseline: 1.0053x; 1.0053x over previous
//
#include <hip/hip_runtime.h>
#include <stdint.h>

// AttentionBlock: GN -> QKV -> softmax(QK^T/sqrt(C)) V -> proj + residual
// B=4, C=256, H=W=64, N=4096, groups=8 (32 ch/group)
// All matmuls bf16 MFMA (fp32 accumulate). fp32 threshold 0.1 absmax.
//
// Round 12 = round 11 + ILP fix: QK accumulator split into 4 independent
// MFMA chains (depth 16 -> 4) so the scheduler can hide ds_read/MFMA latency
// at 1 wave/SIMD. Chunk-major LDS (0 bank conflicts, round 11 verified)
// and all layouts unchanged.

#define B_ 4
#define C_ 256
#define N_ 4096
#define KVB 32

using bf16x8 = __attribute__((ext_vector_type(8))) __bf16;
using f32x4  = __attribute__((ext_vector_type(4))) float;
using f32x16 = __attribute__((ext_vector_type(16))) float;

__device__ __forceinline__ uint16_t f2bf(float f) {
    uint32_t u = __float_as_uint(f);
    u = (u + 0x7fffu + ((u >> 16) & 1u)) >> 16;   // RNE
    return (uint16_t)u;
}

__device__ __forceinline__ f32x4 mfma16(bf16x8 a, bf16x8 b, f32x4 c) {
    return __builtin_amdgcn_mfma_f32_16x16x32_bf16(a, b, c, 0, 0, 0);
}

__device__ __forceinline__ f32x16 mfma32(bf16x8 a, bf16x8 b, f32x16 c) {
    return __builtin_amdgcn_mfma_f32_32x32x16_bf16(a, b, c, 0, 0, 0);
}

__device__ __forceinline__ void gload16(const void* g, void* l) {
    __builtin_amdgcn_global_load_lds(
        (const __attribute__((address_space(1))) uint32_t*)g,
        (__attribute__((address_space(3))) uint32_t*)l, 16, 0, 0);
}

// ---------------- cast weights to bf16 ----------------
__global__ __launch_bounds__(256) void cast_weights(
        const float* __restrict__ qkvw, const float* __restrict__ projw,
        uint16_t* __restrict__ qkvwb, uint16_t* __restrict__ projwb) {
    int i = blockIdx.x * 256 + threadIdx.x;
    if (i < 768 * 256) qkvwb[i] = f2bf(qkvw[i]);
    int j = i - 768 * 256;
    if (j >= 0 && j < 256 * 256) projwb[j] = f2bf(projw[j]);
}

// ---------------- GroupNorm stats, two-stage ----------------
__global__ __launch_bounds__(256) void gn_stats1(const float* __restrict__ x,
                                                 float2* __restrict__ part) {
    int i = blockIdx.x;
    const float4* p = reinterpret_cast<const float4*>(x + (size_t)i * 4096);
    float s = 0.f, ss = 0.f;
    #pragma unroll
    for (int j = 0; j < 4; j++) {
        float4 v = p[threadIdx.x + j * 256];
        s  += v.x + v.y + v.z + v.w;
        ss += v.x*v.x + v.y*v.y + v.z*v.z + v.w*v.w;
    }
    #pragma unroll
    for (int d = 32; d > 0; d >>= 1) { s += __shfl_down(s, d); ss += __shfl_down(ss, d); }
    __shared__ float rs[4], rss[4];
    int wid = threadIdx.x >> 6;
    if ((threadIdx.x & 63) == 0) { rs[wid] = s; rss[wid] = ss; }
    __syncthreads();
    if (threadIdx.x == 0) {
        float2 o;
        o.x = rs[0] + rs[1] + rs[2] + rs[3];
        o.y = rss[0] + rss[1] + rss[2] + rss[3];
        part[i] = o;
    }
}
__global__ __launch_bounds__(1024) void gn_stats2(const float2* __restrict__ part,
                                                  float* __restrict__ stats) {
    int t = threadIdx.x;
    int g = t >> 5, j = t & 31;
    float2 v = part[g * 32 + j];
    float s = v.x, ss = v.y;
    #pragma unroll
    for (int d = 16; d > 0; d >>= 1) { s += __shfl_xor(s, d); ss += __shfl_xor(ss, d); }
    if (j == 0) {
        float mean = s / 131072.f;
        float var  = ss / 131072.f - mean * mean;
        stats[g * 2]     = mean;
        stats[g * 2 + 1] = rsqrtf(var + 1e-5f);
    }
}

// ---------------- GN apply + transpose: hT[b][n][c] bf16 ----------------
__global__ __launch_bounds__(256) void gn_apply(
        const float* __restrict__ x, const float* __restrict__ gnw,
        const float* __restrict__ gnb, const float* __restrict__ stats,
        uint16_t* __restrict__ hT) {
    int nb = blockIdx.x * 64, cb = blockIdx.y * 64, b = blockIdx.z;
    __shared__ uint16_t lds[64][64];          // [n][c]
    int t = threadIdx.x;
    int c_l = t >> 4;
    int n4  = (t & 15) * 4;
    #pragma unroll
    for (int i = 0; i < 4; i++) {
        int c = cb + c_l + 16 * i;
        int sg = b * 8 + (c >> 5);
        float mean = stats[sg * 2], rstd = stats[sg * 2 + 1];
        float sc = gnw[c] * rstd;
        float sh = gnb[c] - mean * sc;
        float4 v = *reinterpret_cast<const float4*>(x + ((size_t)b * C_ + c) * N_ + nb + n4);
        lds[n4 + 0][c_l + 16 * i] = f2bf(fmaf(v.x, sc, sh));
        lds[n4 + 1][c_l + 16 * i] = f2bf(fmaf(v.y, sc, sh));
        lds[n4 + 2][c_l + 16 * i] = f2bf(fmaf(v.z, sc, sh));
        lds[n4 + 3][c_l + 16 * i] = f2bf(fmaf(v.w, sc, sh));
    }
    __syncthreads();
    int n_l = t >> 2, c16 = (t & 3) * 16;
    uint4* dst = reinterpret_cast<uint4*>(hT + ((size_t)b * N_ + nb + n_l) * C_ + cb + c16);
    const uint4* sp = reinterpret_cast<const uint4*>(&lds[n_l][c16]);
    dst[0] = sp[0]; dst[1] = sp[1];
}

// ---------------- QKV GEMM ----------------
// q,k transposed [n][o]; q pre-scaled by 1/16 (softmax scale). v kept [o'][n].
__global__ __launch_bounds__(256) void qkv_gemm(
        const uint16_t* __restrict__ Wb, const float* __restrict__ qkvb,
        const uint16_t* __restrict__ hT, uint16_t* __restrict__ qT,
        uint16_t* __restrict__ kT, uint16_t* __restrict__ vO) {
    int nt = blockIdx.x, ot = blockIdx.y, b = blockIdx.z;
    int lane = threadIdx.x & 63, w = threadIdx.x >> 6;
    int l15 = lane & 15, g = lane >> 4;
    const uint16_t* hTb = hT + (size_t)b * N_ * C_;
    f32x4 z = {0.f, 0.f, 0.f, 0.f};
    f32x4 acc[4] = {z, z, z, z};

    if (ot < 8) {   // q,k : D[row=n][col=o]
        int nrow = nt * 64 + w * 16 + l15;
        const bf16x8* Arow = reinterpret_cast<const bf16x8*>(hTb + (size_t)nrow * C_);
        #pragma unroll
        for (int kk = 0; kk < 8; kk++) {
            bf16x8 a = Arow[kk * 4 + g];
            #pragma unroll
            for (int j = 0; j < 4; j++) {
                int orow = ot * 64 + j * 16 + l15;
                bf16x8 bfr = reinterpret_cast<const bf16x8*>(Wb + (size_t)orow * C_)[kk * 4 + g];
                acc[j] = mfma16(a, bfr, acc[j]);
            }
        }
        #pragma unroll
        for (int j = 0; j < 4; j++) {
            int o = ot * 64 + j * 16 + l15;
            float bias = qkvb[o];
            bool isq = (o < 256);
            float scl = isq ? 0.0625f : 1.0f;
            uint16_t* dst = isq ? (qT + (size_t)b * N_ * C_ + o)
                                : (kT + (size_t)b * N_ * C_ + (o - 256));
            #pragma unroll
            for (int r = 0; r < 4; r++) {
                int n = nt * 64 + w * 16 + g * 4 + r;
                dst[(size_t)n * C_] = f2bf((acc[j][r] + bias) * scl);
            }
        }
    } else {        // v : D[row=o'][col=n]
        int orow = ot * 64 + w * 16 + l15;   // 512..767
        const bf16x8* Arow = reinterpret_cast<const bf16x8*>(Wb + (size_t)orow * C_);
        #pragma unroll
        for (int kk = 0; kk < 8; kk++) {
            bf16x8 a = Arow[kk * 4 + g];
            #pragma unroll
            for (int j = 0; j < 4; j++) {
                int nrow = nt * 64 + j * 16 + l15;
                bf16x8 bfr = reinterpret_cast<const bf16x8*>(hTb + (size_t)nrow * C_)[kk * 4 + g];
                acc[j] = mfma16(a, bfr, acc[j]);
            }
        }
        #pragma unroll
        for (int j = 0; j < 4; j++) {
            #pragma unroll
            for (int r = 0; r < 4; r++) {
                int o = ot * 64 + w * 16 + g * 4 + r;
                int n = nt * 64 + j * 16 + l15;
                vO[(size_t)b * C_ * N_ + (size_t)(o - 512) * N_ + n] = f2bf(acc[j][r] + qkvb[o]);
            }
        }
    }
}

// ---------------- Flash attention: 32x32 MFMA, chunk-major LDS, ILP ----------
// Block 256 thr = 4 waves: rowgroup rg = w&1 (32 q-rows), key half h = w>>1.
//   Kt: [32 chunk16B][32 key][8 ch]  (chunk-major, conflict-free)
//   Vt: [4 chunk16B][256 ch][8 key]
// QK^T uses 4 INDEPENDENT accumulator chains (depth 4 each) so ds_read and
// MFMA latency overlap across chains at 1 wave/SIMD. PV: 8 indep chains.
// Static-max softmax (m=0, q pre-scaled); epilogue merges halves via LDS.
__global__ __launch_bounds__(256, 1) void attn_kernel(
        const uint16_t* __restrict__ qT, const uint16_t* __restrict__ kT,
        const uint16_t* __restrict__ vO, uint16_t* __restrict__ h2T) {
    int blk = blockIdx.x;
    int xx = blk & 7;
    int b  = xx >> 1;
    int qt = (blk >> 3) * 2 + (xx & 1);       // 0..63
    int lane = threadIdx.x & 63, w = threadIdx.x >> 6;   // w in 0..3
    int rg = w & 1, h = w >> 1;
    int l31 = lane & 31, g5 = lane >> 5;
    const uint16_t* qTb = qT + (size_t)b * N_ * C_;
    const uint16_t* kTb = kT + (size_t)b * N_ * C_;
    const uint16_t* vb  = vO + (size_t)b * C_ * N_;
    int nb = qt * 64 + rg * 32;

    __shared__ __align__(16) char smem[141312];
    uint16_t* KtB = reinterpret_cast<uint16_t*>(smem);            // [2buf][2h][8192]
    uint16_t* VtB = reinterpret_cast<uint16_t*>(smem + 65536);    // [2buf][2h][8192]
    uint16_t* plw = reinterpret_cast<uint16_t*>(smem + 131072) + w * 1280;  // [32][40]

    // Q fragments: A[row=l31][k=s*16 + g5*8 + j]
    bf16x8 afr[16];
    {
        const uint16_t* qrow = qTb + (size_t)(nb + l31) * C_;
        #pragma unroll
        for (int s = 0; s < 16; s++)
            afr[s] = *reinterpret_cast<const bf16x8*>(qrow + s * 16 + g5 * 8);
    }

    f32x16 acc[8];
    #pragma unroll
    for (int i = 0; i < 8; i++) acc[i] = (f32x16){};
    float lsum[16];
    #pragma unroll
    for (int i = 0; i < 16; i++) lsum[i] = 0.f;

    // wave (rg,h) stages half h's next tile (linear dests, chunk-major)
    auto stage = [&](int bufh, int mb) {
        uint16_t* Ktp = KtB + bufh * 8192;
        uint16_t* Vtp = VtB + bufh * 8192;
        #pragma unroll
        for (int i = 0; i < 8; i++) {         // K: 2 chunk-cols x 32 keys / instr
            int c2 = rg * 16 + i * 2;
            gload16(kTb + (size_t)(mb + l31) * C_ + (c2 + g5) * 8, Ktp + c2 * 256);
        }
        #pragma unroll
        for (int i = 0; i < 8; i++) {         // V: 1 chunk x 64 ch / instr
            int c   = i >> 1;
            int cb3 = rg * 128 + (i & 1) * 64;
            gload16(vb + (size_t)(cb3 + lane) * N_ + mb + c * 8, Vtp + c * 2048 + cb3 * 8);
        }
    };

    stage(h, h * 64 * KVB);
    __syncthreads();

    for (int mt = 0; mt < 64; mt++) {
        int buf = mt & 1;
        if (mt + 1 < 64) stage((buf ^ 1) * 2 + h, (h * 64 + mt + 1) * KVB);
        const uint16_t* Ktp = KtB + (buf * 2 + h) * 8192;
        const uint16_t* Vtp = VtB + (buf * 2 + h) * 8192;

        // ---- QK^T: 4 independent accumulator chains (ILP) ----
        f32x16 sc0 = (f32x16){}, sc1 = (f32x16){}, sc2 = (f32x16){}, sc3 = (f32x16){};
        #pragma unroll
        for (int s4 = 0; s4 < 4; s4++) {
            bf16x8 k0 = *reinterpret_cast<const bf16x8*>(Ktp + ((s4 * 4 + 0) * 2 + g5) * 256 + l31 * 8);
            bf16x8 k1 = *reinterpret_cast<const bf16x8*>(Ktp + ((s4 * 4 + 1) * 2 + g5) * 256 + l31 * 8);
            bf16x8 k2 = *reinterpret_cast<const bf16x8*>(Ktp + ((s4 * 4 + 2) * 2 + g5) * 256 + l31 * 8);
            bf16x8 k3 = *reinterpret_cast<const bf16x8*>(Ktp + ((s4 * 4 + 3) * 2 + g5) * 256 + l31 * 8);
            sc0 = mfma32(afr[s4 * 4 + 0], k0, sc0);
            sc1 = mfma32(afr[s4 * 4 + 1], k1, sc1);
            sc2 = mfma32(afr[s4 * 4 + 2], k2, sc2);
            sc3 = mfma32(afr[s4 * 4 + 3], k3, sc3);
        }
        f32x16 sc = (sc0 + sc1) + (sc2 + sc3);

        // ---- static-max softmax: p=exp(score), lane-local l partials ----
        #pragma unroll
        for (int reg = 0; reg < 16; reg++) {
            float p = __expf(sc[reg]);
            lsum[reg] += p;
            int row = (reg & 3) + 8 * (reg >> 2) + 4 * g5;
            plw[row * 40 + l31] = f2bf(p);
        }

        bf16x8 pf0 = *reinterpret_cast<const bf16x8*>(plw + l31 * 40 + g5 * 8);
        bf16x8 pf1 = *reinterpret_cast<const bf16x8*>(plw + l31 * 40 + 16 + g5 * 8);

        // ---- PV: A=V chunk-major (contiguous), B=P^T; 8 indep chains ----
        #pragma unroll
        for (int ct = 0; ct < 8; ct++) {
            int ch8 = (ct * 32 + l31) * 8;
            bf16x8 v0 = *reinterpret_cast<const bf16x8*>(Vtp + g5 * 2048 + ch8);
            bf16x8 v1 = *reinterpret_cast<const bf16x8*>(Vtp + (2 + g5) * 2048 + ch8);
            acc[ct] = mfma32(v0, pf0, acc[ct]);
            acc[ct] = mfma32(v1, pf1, acc[ct]);
        }

        __syncthreads();   // drains vmcnt (stage done); both halves advance
    }

    // ---- epilogue ----
    #pragma unroll
    for (int d = 1; d < 32; d <<= 1) {
        #pragma unroll
        for (int reg = 0; reg < 16; reg++) lsum[reg] += __shfl_xor(lsum[reg], d);
    }
    float* Olds = reinterpret_cast<float*>(smem);            // [2rg][32 qrow][260]
    float* lbuf = reinterpret_cast<float*>(smem + 66560);    // [2h][2rg][32]
    if ((lane & 31) == 0) {
        #pragma unroll
        for (int reg = 0; reg < 16; reg++) {
            int row = (reg & 3) + 8 * (reg >> 2) + 4 * g5;
            lbuf[(h * 2 + rg) * 32 + row] = lsum[reg];
        }
    }
    if (h == 1) {
        #pragma unroll
        for (int ct = 0; ct < 8; ct++) {
            #pragma unroll
            for (int qd = 0; qd < 4; qd++) {
                f32x4 v = {acc[ct][qd * 4 + 0], acc[ct][qd * 4 + 1],
                           acc[ct][qd * 4 + 2], acc[ct][qd * 4 + 3]};
                *reinterpret_cast<f32x4*>(
                    &Olds[(size_t)(rg * 32 + l31) * 260 + ct * 32 + qd * 8 + 4 * g5]) = v;
            }
        }
    }
    __syncthreads();
    if (h == 0) {
        float inv = 1.0f / (lbuf[rg * 32 + l31] + lbuf[(2 + rg) * 32 + l31]);
        uint16_t* rowp = h2T + ((size_t)b * N_ + nb + l31) * C_;
        #pragma unroll
        for (int ct = 0; ct < 8; ct++) {
            #pragma unroll
            for (int qd = 0; qd < 4; qd++) {
                f32x4 o = *reinterpret_cast<const f32x4*>(
                    &Olds[(size_t)(rg * 32 + l31) * 260 + ct * 32 + qd * 8 + 4 * g5]);
                uint32_t lo = f2bf((acc[ct][qd * 4 + 0] + o[0]) * inv) |
                              ((uint32_t)f2bf((acc[ct][qd * 4 + 1] + o[1]) * inv) << 16);
                uint32_t hi = f2bf((acc[ct][qd * 4 + 2] + o[2]) * inv) |
                              ((uint32_t)f2bf((acc[ct][qd * 4 + 3] + o[3]) * inv) << 16);
                uint2 val = {lo, hi};
                *reinterpret_cast<uint2*>(rowp + ct * 32 + qd * 8 + 4 * g5) = val;
            }
        }
    }
}

// ---------------- proj GEMM + bias + residual ----------------
__global__ __launch_bounds__(256) void proj_gemm(
        const uint16_t* __restrict__ Pwb, const float* __restrict__ pb,
        const uint16_t* __restrict__ h2T, const float* __restrict__ x,
        float* __restrict__ out) {
    int nt = blockIdx.x, ct = blockIdx.y, b = blockIdx.z;
    int lane = threadIdx.x & 63, w = threadIdx.x >> 6;
    int l15 = lane & 15, g = lane >> 4;
    const uint16_t* h2Tb = h2T + (size_t)b * N_ * C_;
    f32x4 z = {0.f, 0.f, 0.f, 0.f};
    f32x4 acc[4] = {z, z, z, z};
    int crow = ct * 64 + w * 16 + l15;
    const bf16x8* Arow = reinterpret_cast<const bf16x8*>(Pwb + (size_t)crow * C_);
    #pragma unroll
    for (int kk = 0; kk < 8; kk++) {
        bf16x8 a = Arow[kk * 4 + g];
        #pragma unroll
        for (int j = 0; j < 4; j++) {
            bf16x8 bfr = reinterpret_cast<const bf16x8*>(
                h2Tb + (size_t)(nt * 64 + j * 16 + l15) * C_)[kk * 4 + g];
            acc[j] = mfma16(a, bfr, acc[j]);
        }
    }
    #pragma unroll
    for (int j = 0; j < 4; j++) {
        #pragma unroll
        for (int r = 0; r < 4; r++) {
            int c = ct * 64 + w * 16 + g * 4 + r;
            int n = nt * 64 + j * 16 + l15;
            size_t idx = ((size_t)b * C_ + c) * N_ + n;
            out[idx] = x[idx] + acc[j][r] + pb[c];
        }
    }
}

extern "C" void kernel_launch(void* const* d_in, const int* in_sizes, int n_in,
                              void* d_out, int out_size, void* d_ws, size_t ws_size,
                              hipStream_t stream) {
    const float* x      = (const float*)d_in[0];
    const float* gn_w   = (const float*)d_in[1];
    const float* gn_b   = (const float*)d_in[2];
    const float* qkv_w  = (const float*)d_in[3];
    const float* qkv_b  = (const float*)d_in[4];
    const float* proj_w = (const float*)d_in[5];
    const float* proj_b = (const float*)d_in[6];
    float* out = (float*)d_out;

    char* ws = (char*)d_ws;
    float*    stats  = (float*)(ws);                          // 256 B
    float2*   part   = (float2*)(ws + 8192);                  // 8 KB
    uint16_t* qkvwb  = (uint16_t*)(ws + 65536);               // 384 KB
    uint16_t* projwb = (uint16_t*)(ws + 65536 + 768 * 256 * 2);
    uint16_t* hT     = (uint16_t*)(ws + (size_t)(1)  * (1 << 20));  // 8 MB [B][N][C]
    uint16_t* qT     = (uint16_t*)(ws + (size_t)(9)  * (1 << 20));  // 8 MB [B][N][C]
    uint16_t* kT     = (uint16_t*)(ws + (size_t)(17) * (1 << 20));  // 8 MB [B][N][C]
    uint16_t* vO     = (uint16_t*)(ws + (size_t)(25) * (1 << 20));  // 8 MB [B][C][N]
    uint16_t* h2T    = (uint16_t*)(ws + (size_t)(33) * (1 << 20));  // 8 MB [B][N][C]

    cast_weights<<<dim3(1024), dim3(256), 0, stream>>>(qkv_w, proj_w, qkvwb, projwb);
    gn_stats1<<<dim3(1024), dim3(256), 0, stream>>>(x, part);
    gn_stats2<<<dim3(1), dim3(1024), 0, stream>>>(part, stats);
    gn_apply<<<dim3(64, 4, 4), dim3(256), 0, stream>>>(x, gn_w, gn_b, stats, hT);
    qkv_gemm<<<dim3(64, 12, 4), dim3(256), 0, stream>>>(qkvwb, qkv_b, hT, qT, kT, vO);
    attn_kernel<<<dim3(256), dim3(256), 0, stream>>>(qT, kT, vO, h2T);
    proj_gemm<<<dim3(64, 4, 4), dim3(256), 0, stream>>>(projwb, proj_b, h2T, x, out);
}